// Round 13
// baseline (203.065 us; speedup 1.0000x reference)
//
#include <hip/hip_runtime.h>
#include <hip/hip_bf16.h>

static constexpr int KC   = 9;    // kernel bins
static constexpr int CIN  = 32;   // input channels
static constexpr int CA   = 24;   // branch-a out channels
static constexpr int CB   = 8;    // branch-b out channels
static constexpr int COUT = 32;   // CA + CB
static constexpr int KCC  = KC * CIN;       // 288
static constexpr int SPP  = 2 * KCC;        // 576 bf16 S entries per point

// ---------------------------------------------------------------------------
// Prep: CSR row pointer + per-edge importance pre-gather + W pack, one launch.
// ---------------------------------------------------------------------------
__global__ void prep(const int* __restrict__ oidx, const int* __restrict__ nidx,
                     const float* __restrict__ importance,
                     const float* __restrict__ Wa, const float* __restrict__ Wb,
                     int* __restrict__ rp, float* __restrict__ imp_e,
                     float* __restrict__ Wc, int E, int nout) {
    int e = blockIdx.x * blockDim.x + threadIdx.x;
    if (e < E) {
        int cur  = oidx[e];
        int prev = (e == 0) ? -1 : oidx[e - 1];
        for (int id = prev + 1; id <= cur; ++id) rp[id] = e;
        if (e == E - 1) {
            for (int id = cur + 1; id <= nout; ++id) rp[id] = E;
        }
        imp_e[e] = importance[nidx[e]];
        if (e < KCC * COUT) {
            int f  = e & (COUT - 1);
            int kc = e >> 5;
            Wc[e] = (f < CA) ? Wa[kc * CA + f] : Wb[kc * CB + (f - CA)];
        }
    }
}

// ---------------------------------------------------------------------------
// Kernel A: branch-free scalar-mask accumulation. One wave per point
// (grid-stride); one edge per wave "slot", 4 edges unrolled straight-line
// (all loads clustered -> deep MLP, no basic-block fragmentation).
// q is wave-uniform -> mk = (q==k) is SALU s_cmp+s_cselect (co-issued);
// acc[k] = fmaf(mk, v, acc[k]) is one v_fmac with SGPR multiplier.
// Half 0 accumulates Sa (v=f), half 1 accumulates Sb (v=f*m).
// ---------------------------------------------------------------------------
__global__ __launch_bounds__(256) void accum_v(
    const float* __restrict__ feats, const float* __restrict__ imp_e,
    const int* __restrict__ nidx, const int* __restrict__ nkidx,
    const int* __restrict__ rp,
    __hip_bfloat16* __restrict__ S, float* __restrict__ impAcc, int nout)
{
    const int lane = threadIdx.x & 63;
    const int c    = lane & 31;
    const int h    = lane >> 5;
    int gw = (blockIdx.x * 256 + threadIdx.x) >> 6;
    gw = __builtin_amdgcn_readfirstlane(gw);
    const int NW = (gridDim.x * 256) >> 6;

    for (int n = gw; n < nout; n += NW) {
        const int start = rp[n];
        const int end   = rp[n + 1];

        float acc[KC];
#pragma unroll
        for (int k = 0; k < KC; ++k) acc[k] = 0.f;
        float accImp = 0.f;

        for (int e = start; e < end; e += 4) {
            // clamped edge ids (end > start whenever this loop runs)
            const int last = end - 1;
            int ea = e;
            int eb = (e + 1 < end) ? e + 1 : last;
            int ec = (e + 2 < end) ? e + 2 : last;
            int ed = (e + 3 < end) ? e + 3 : last;
            // all metadata loads issued together (wave-uniform -> s_load)
            int qa = __builtin_amdgcn_readfirstlane(nkidx[ea]);
            int qb = __builtin_amdgcn_readfirstlane(nkidx[eb]);
            int qc = __builtin_amdgcn_readfirstlane(nkidx[ec]);
            int qd = __builtin_amdgcn_readfirstlane(nkidx[ed]);
            int ia = nidx[ea], ib = nidx[eb], ic = nidx[ec], id = nidx[ed];
            float ma = imp_e[ea], mb = imp_e[eb], mc = imp_e[ec], md = imp_e[ed];
            // 4 independent row gathers in flight
            float fa = feats[(size_t)ia * CIN + c];
            float fb = feats[(size_t)ib * CIN + c];
            float fc = feats[(size_t)ic * CIN + c];
            float fd = feats[(size_t)id * CIN + c];
            // zero invalid (clamped) edges - data masking, no control flow
            if (e + 1 >= end) { fb = 0.f; mb = 0.f; }
            if (e + 2 >= end) { fc = 0.f; mc = 0.f; }
            if (e + 3 >= end) { fd = 0.f; md = 0.f; }
            accImp += (ma + mb) + (mc + md);
            float va = h ? fa * ma : fa;
            float vb = h ? fb * mb : fb;
            float vc = h ? fc * mc : fc;
            float vd = h ? fd * md : fd;
#pragma unroll
            for (int k = 0; k < KC; ++k) {
                float mka = (qa == k) ? 1.0f : 0.0f;   // SALU select
                float mkb = (qb == k) ? 1.0f : 0.0f;
                float mkc = (qc == k) ? 1.0f : 0.0f;
                float mkd = (qd == k) ? 1.0f : 0.0f;
                acc[k] = fmaf(mka, va, acc[k]);        // v_fmac, sgpr mult
                acc[k] = fmaf(mkb, vb, acc[k]);
                acc[k] = fmaf(mkc, vc, acc[k]);
                acc[k] = fmaf(mkd, vd, acc[k]);
            }
        }

        // flush: one wave-wide bf16 store per k (h selects Sa/Sb region)
        __hip_bfloat16* Sp = S + (size_t)n * SPP + h * KCC + c;
#pragma unroll
        for (int k = 0; k < KC; ++k) Sp[k * CIN] = __float2bfloat16(acc[k]);
        if (lane == 0) impAcc[n] = accImp;
    }
}

// ---------------------------------------------------------------------------
// Kernel B: lane-per-point epilogue (round-10/11 winner), bf16 S input.
// W addresses wave-uniform -> s_load through K$; S per-lane row stream.
// ---------------------------------------------------------------------------
__global__ __launch_bounds__(256) void epilogue_g(
    const __hip_bfloat16* __restrict__ S, const float* __restrict__ impAcc,
    const float* __restrict__ Wc, const float* __restrict__ ba,
    const float* __restrict__ bb,
    float* __restrict__ outf, float* __restrict__ outimp, int nout)
{
    const int gtid   = blockIdx.x * 256 + threadIdx.x;
    const bool valid = (gtid < nout);
    const int n      = valid ? gtid : (nout - 1);

    const unsigned short* Sp =
        reinterpret_cast<const unsigned short*>(S + (size_t)n * SPP);

    float acc[COUT];
#pragma unroll
    for (int j = 0; j < COUT; ++j) acc[j] = 0.f;

    for (int t = 0; t < KCC; t += 8) {
        uint4 ua = *reinterpret_cast<const uint4*>(Sp + t);
        uint4 ub = *reinterpret_cast<const uint4*>(Sp + KCC + t);
        unsigned int uaw[4] = {ua.x, ua.y, ua.z, ua.w};
        unsigned int ubw[4] = {ub.x, ub.y, ub.z, ub.w};
        float sav[8], sbv[8];
#pragma unroll
        for (int p = 0; p < 4; ++p) {
            sav[2 * p]     = __uint_as_float(uaw[p] << 16);
            sav[2 * p + 1] = __uint_as_float(uaw[p] & 0xffff0000u);
            sbv[2 * p]     = __uint_as_float(ubw[p] << 16);
            sbv[2 * p + 1] = __uint_as_float(ubw[p] & 0xffff0000u);
        }
#pragma unroll
        for (int u = 0; u < 8; ++u) {
            const float* w = Wc + (t + u) * COUT;   // wave-uniform -> s_load
#pragma unroll
            for (int j = 0; j < CA; ++j) acc[j] = fmaf(sav[u], w[j], acc[j]);
#pragma unroll
            for (int j = 0; j < CB; ++j)
                acc[CA + j] = fmaf(sbv[u], w[CA + j], acc[CA + j]);
        }
    }

    float impTot = impAcc[n];
    float denom  = impTot > 0.f ? impTot : 1.f;

    if (valid) {
        float res[COUT];
#pragma unroll
        for (int j = 0; j < CA; ++j) res[j] = fmaxf(acc[j] + ba[j], 0.f);
#pragma unroll
        for (int j = 0; j < CB; ++j)
            res[CA + j] = fmaxf(acc[CA + j] / denom + bb[j], 0.f);
        float4* op = reinterpret_cast<float4*>(outf + (size_t)n * COUT);
#pragma unroll
        for (int j4 = 0; j4 < 8; ++j4)
            op[j4] = make_float4(res[4 * j4], res[4 * j4 + 1],
                                 res[4 * j4 + 2], res[4 * j4 + 3]);
        outimp[n] = impTot;
    }
}

// ===========================================================================
// Fallback (round-6 fused kernel) if ws can't hold the scratch.
// ===========================================================================
static constexpr int WSTR = KC * CIN + 4;
static constexpr int PPB = 16;
static constexpr int TPB = 512;
static constexpr int NHW = TPB / 32;

__global__ void build_rowptr_fb(const int* __restrict__ oidx, int* __restrict__ rp,
                                int E, int nout) {
    int e = blockIdx.x * blockDim.x + threadIdx.x;
    if (e >= E) return;
    int cur  = oidx[e];
    int prev = (e == 0) ? -1 : oidx[e - 1];
    for (int id = prev + 1; id <= cur; ++id) rp[id] = e;
    if (e == E - 1) {
        for (int id = cur + 1; id <= nout; ++id) rp[id] = E;
    }
}

__global__ void pack_weights_fkc(const float* __restrict__ Wa,
                                 const float* __restrict__ Wb,
                                 float* __restrict__ Wt) {
    int t = blockIdx.x * blockDim.x + threadIdx.x;
    if (t >= COUT * KC * CIN) return;
    int f = t / (KC * CIN);
    int r = t % (KC * CIN);
    Wt[t] = (f < CA) ? Wa[r * CA + f] : Wb[r * CB + (f - CA)];
}

__global__ __launch_bounds__(TPB) void fused_block(
    const float* __restrict__ feats, const float* __restrict__ importance,
    const float* __restrict__ Wt, const float* __restrict__ ba,
    const float* __restrict__ bb,
    const int* __restrict__ nidx, const int* __restrict__ nkidx,
    const int* __restrict__ noidx, const int* __restrict__ rp,
    float* __restrict__ outf, float* __restrict__ outimp, int nout)
{
    __shared__ __align__(16) float sW[COUT * WSTR];
    __shared__ __align__(16) float sS[PPB][2][KC * CIN];
    __shared__ float sImp[PPB];

    const int tid = threadIdx.x;
    const int hw  = tid >> 5;
    const int c   = tid & 31;
    const int p0  = blockIdx.x * PPB;

    {
        float* pS = &sS[0][0][0];
        for (int i = tid; i < PPB * 2 * KC * CIN; i += TPB) pS[i] = 0.f;
        for (int i = tid; i < COUT * KC * CIN; i += TPB) {
            int f = i / (KC * CIN);
            int r = i % (KC * CIN);
            sW[f * WSTR + r] = Wt[i];
        }
        if (tid < PPB) sImp[tid] = 0.f;
    }
    __syncthreads();

    const int pend   = (p0 + PPB < nout) ? (p0 + PPB) : nout;
    const int estart = rp[p0];
    const int eend   = rp[pend];
    const int cnt    = eend - estart;
    const int per    = (cnt + NHW - 1) / NHW;
    int a = estart + hw * per;
    int b = a + per; if (b > eend) b = eend;

    float* S0 = &sS[0][0][0];
    for (int e = a; e < b; ++e) {
        int   n0 = noidx[e], i0 = nidx[e], q0 = nkidx[e];
        float m0 = importance[i0];
        float f0 = feats[(size_t)i0 * CIN + c];
        float* bp = S0 + (n0 - p0) * (2 * KC * CIN) + q0 * CIN + c;
        atomicAdd(bp, f0);
        atomicAdd(bp + KC * CIN, f0 * m0);
        if (c == 0) atomicAdd(&sImp[n0 - p0], m0);
    }
    __syncthreads();

    const int wave = tid >> 6;
    const int lane = tid & 63;
    const int f    = lane & 31;
    const int h    = lane >> 5;
#pragma unroll
    for (int rep = 0; rep < 2; ++rep) {
        const int slot = wave * 2 + rep;
        const int n    = p0 + slot;
        if (n >= nout) break;
        float impTot = sImp[slot];
        float denom  = impTot > 0.f ? impTot : 1.f;
        const float* Sbase = &sS[slot][(f < CA) ? 0 : 1][0];
        const float* Wbase = sW + f * WSTR;
        float acc = 0.f;
#pragma unroll
        for (int k = 0; k < KC; ++k) {
            int off = k * CIN + h * 16;
#pragma unroll
            for (int j = 0; j < 16; ++j) acc = fmaf(Sbase[off + j], Wbase[off + j], acc);
        }
        float tot = acc + __shfl_xor(acc, 32, 64);
        if (h == 0) {
            float res = (f < CA) ? (tot + ba[f]) : (tot / denom + bb[f - CA]);
            outf[(size_t)n * COUT + f] = fmaxf(res, 0.f);
        }
        if (lane == 0) outimp[n] = impTot;
    }
}

// ---------------------------------------------------------------------------
extern "C" void kernel_launch(void* const* d_in, const int* in_sizes, int n_in,
                              void* d_out, int out_size, void* d_ws, size_t ws_size,
                              hipStream_t stream) {
    const float* feats      = (const float*)d_in[0];
    const float* importance = (const float*)d_in[1];
    const float* Wa         = (const float*)d_in[2];
    const float* ba         = (const float*)d_in[3];
    const float* Wb         = (const float*)d_in[4];
    const float* bb         = (const float*)d_in[5];
    const int*   nidx       = (const int*)d_in[6];
    const int*   nkidx      = (const int*)d_in[7];
    const int*   noidx      = (const int*)d_in[8];

    const int E    = in_sizes[6];
    const int nout = out_size / (COUT + 1);

    float* outf   = (float*)d_out;
    float* outimp = outf + (size_t)nout * COUT;

    // ws: S bf16 [nout*576] | impAcc [nout] | Wc [288*32] | rp [nout+1] | imp_e [E]
    const size_t off_imp = ((size_t)nout * SPP * sizeof(__hip_bfloat16) + 255) & ~(size_t)255;
    const size_t off_wc  = (off_imp + (size_t)nout * sizeof(float) + 255) & ~(size_t)255;
    const size_t off_rp  = (off_wc + (size_t)KCC * COUT * sizeof(float) + 255) & ~(size_t)255;
    const size_t off_ie  = (off_rp + (size_t)(nout + 1) * sizeof(int) + 255) & ~(size_t)255;
    const size_t need    = off_ie + (size_t)E * sizeof(float);

    if (ws_size >= need) {
        __hip_bfloat16* S = (__hip_bfloat16*)d_ws;
        float* impAcc = (float*)((char*)d_ws + off_imp);
        float* Wc     = (float*)((char*)d_ws + off_wc);
        int*   rp     = (int*)((char*)d_ws + off_rp);
        float* imp_e  = (float*)((char*)d_ws + off_ie);

        prep<<<(E + 255) / 256, 256, 0, stream>>>(
            noidx, nidx, importance, Wa, Wb, rp, imp_e, Wc, E, nout);
        accum_v<<<2048, 256, 0, stream>>>(
            feats, imp_e, nidx, nkidx, rp, S, impAcc, nout);
        epilogue_g<<<(nout + 255) / 256, 256, 0, stream>>>(
            S, impAcc, Wc, ba, bb, outf, outimp, nout);
    } else {
        int*   rp = (int*)d_ws;
        size_t rp_bytes = ((size_t)(nout + 1) * sizeof(int) + 255) & ~(size_t)255;
        float* Wt = (float*)((char*)d_ws + rp_bytes);

        build_rowptr_fb<<<(E + 255) / 256, 256, 0, stream>>>(noidx, rp, E, nout);
        pack_weights_fkc<<<(COUT * KC * CIN + 255) / 256, 256, 0, stream>>>(Wa, Wb, Wt);
        fused_block<<<(nout + PPB - 1) / PPB, TPB, 0, stream>>>(
            feats, importance, Wt, ba, bb, nidx, nkidx, noidx, rp,
            outf, outimp, nout);
    }
}

// Round 14
// 180.002 us; speedup vs baseline: 1.1281x; 1.1281x over previous
//
#include <hip/hip_runtime.h>
#include <hip/hip_bf16.h>

static constexpr int KC   = 9;    // kernel bins
static constexpr int CIN  = 32;   // input channels
static constexpr int CA   = 24;   // branch-a out channels
static constexpr int CB   = 8;    // branch-b out channels
static constexpr int COUT = 32;   // CA + CB
static constexpr int KCC  = KC * CIN;       // 288
static constexpr int SPP  = 2 * KCC;        // 576 bf16 S entries per point
static constexpr int PPW  = 13;   // points per wave (contiguous)

// ---------------------------------------------------------------------------
// Prep: CSR row pointer + per-edge importance pre-gather + W pack, one launch.
// ---------------------------------------------------------------------------
__global__ void prep(const int* __restrict__ oidx, const int* __restrict__ nidx,
                     const float* __restrict__ importance,
                     const float* __restrict__ Wa, const float* __restrict__ Wb,
                     int* __restrict__ rp, float* __restrict__ imp_e,
                     float* __restrict__ Wc, int E, int nout) {
    int e = blockIdx.x * blockDim.x + threadIdx.x;
    if (e < E) {
        int cur  = oidx[e];
        int prev = (e == 0) ? -1 : oidx[e - 1];
        for (int id = prev + 1; id <= cur; ++id) rp[id] = e;
        if (e == E - 1) {
            for (int id = cur + 1; id <= nout; ++id) rp[id] = E;
        }
        imp_e[e] = importance[nidx[e]];
        if (e < KCC * COUT) {
            int f  = e & (COUT - 1);
            int kc = e >> 5;
            Wc[e] = (f < CA) ? Wa[kc * CA + f] : Wb[kc * CB + (f - CA)];
        }
    }
}

// uniform-q conditional add: q is in SGPR -> scalar branch chain, ~1 v_add
// executed per edge (round-11's measured-best accumulator).
#define ACC_ADD(Q, V)                              \
    do {                                           \
        if      ((Q) == 0) acc[0] += (V);          \
        else if ((Q) == 1) acc[1] += (V);          \
        else if ((Q) == 2) acc[2] += (V);          \
        else if ((Q) == 3) acc[3] += (V);          \
        else if ((Q) == 4) acc[4] += (V);          \
        else if ((Q) == 5) acc[5] += (V);          \
        else if ((Q) == 6) acc[6] += (V);          \
        else if ((Q) == 7) acc[7] += (V);          \
        else               acc[8] += (V);          \
    } while (0)

// ---------------------------------------------------------------------------
// Kernel A: contiguous-stream scalar-q accumulation.
// Wave w owns points [w*PPW, (w+1)*PPW): its edge range is one contiguous
// stream (sequential metadata lines, like ab_stream). Chained rp: one
// L1-warm uniform load per point. 8-edge unroll: 8 gathers in flight.
// Half 0 accumulates Sa (v=f), half 1 Sb (v=f*m). bf16 flush stores.
// ---------------------------------------------------------------------------
__global__ __launch_bounds__(256) void accum_w(
    const float* __restrict__ feats, const float* __restrict__ imp_e,
    const int* __restrict__ nidx, const int* __restrict__ nkidx,
    const int* __restrict__ rp,
    __hip_bfloat16* __restrict__ S, float* __restrict__ impAcc, int nout)
{
    const int lane = threadIdx.x & 63;
    const int c    = lane & 31;
    const int h    = lane >> 5;
    int wid = (blockIdx.x * 256 + threadIdx.x) >> 6;
    wid = __builtin_amdgcn_readfirstlane(wid);

    const int p0 = wid * PPW;
    if (p0 >= nout) return;
    const int p1 = (p0 + PPW < nout) ? (p0 + PPW) : nout;

    int start = rp[p0];                        // uniform; subsequent chained
    for (int n = p0; n < p1; ++n) {
        const int end = rp[n + 1];             // L1-warm uniform load

        float acc[KC];
#pragma unroll
        for (int k = 0; k < KC; ++k) acc[k] = 0.f;
        float accImp = 0.f;

        for (int e = start; e < end; e += 8) {
            const int last = end - 1;
            int e1 = (e + 1 < end) ? e + 1 : last;
            int e2 = (e + 2 < end) ? e + 2 : last;
            int e3 = (e + 3 < end) ? e + 3 : last;
            int e4 = (e + 4 < end) ? e + 4 : last;
            int e5 = (e + 5 < end) ? e + 5 : last;
            int e6 = (e + 6 < end) ? e + 6 : last;
            int e7 = (e + 7 < end) ? e + 7 : last;
            // metadata (uniform, sequential lines)
            int q0 = __builtin_amdgcn_readfirstlane(nkidx[e]);
            int q1 = __builtin_amdgcn_readfirstlane(nkidx[e1]);
            int q2 = __builtin_amdgcn_readfirstlane(nkidx[e2]);
            int q3 = __builtin_amdgcn_readfirstlane(nkidx[e3]);
            int q4 = __builtin_amdgcn_readfirstlane(nkidx[e4]);
            int q5 = __builtin_amdgcn_readfirstlane(nkidx[e5]);
            int q6 = __builtin_amdgcn_readfirstlane(nkidx[e6]);
            int q7 = __builtin_amdgcn_readfirstlane(nkidx[e7]);
            int i0 = nidx[e],  i1 = nidx[e1], i2 = nidx[e2], i3 = nidx[e3];
            int i4 = nidx[e4], i5 = nidx[e5], i6 = nidx[e6], i7 = nidx[e7];
            float m0 = imp_e[e],  m1 = imp_e[e1], m2 = imp_e[e2], m3 = imp_e[e3];
            float m4 = imp_e[e4], m5 = imp_e[e5], m6 = imp_e[e6], m7 = imp_e[e7];
            // 8 independent 128B row gathers in flight
            float f0 = feats[(size_t)i0 * CIN + c];
            float f1 = feats[(size_t)i1 * CIN + c];
            float f2 = feats[(size_t)i2 * CIN + c];
            float f3 = feats[(size_t)i3 * CIN + c];
            float f4 = feats[(size_t)i4 * CIN + c];
            float f5 = feats[(size_t)i5 * CIN + c];
            float f6 = feats[(size_t)i6 * CIN + c];
            float f7 = feats[(size_t)i7 * CIN + c];
            // mask clamped (invalid) edges - data, not control flow
            if (e + 1 >= end) { f1 = 0.f; m1 = 0.f; }
            if (e + 2 >= end) { f2 = 0.f; m2 = 0.f; }
            if (e + 3 >= end) { f3 = 0.f; m3 = 0.f; }
            if (e + 4 >= end) { f4 = 0.f; m4 = 0.f; }
            if (e + 5 >= end) { f5 = 0.f; m5 = 0.f; }
            if (e + 6 >= end) { f6 = 0.f; m6 = 0.f; }
            if (e + 7 >= end) { f7 = 0.f; m7 = 0.f; }
            accImp += ((m0 + m1) + (m2 + m3)) + ((m4 + m5) + (m6 + m7));
            float v0 = h ? f0 * m0 : f0;
            float v1 = h ? f1 * m1 : f1;
            float v2 = h ? f2 * m2 : f2;
            float v3 = h ? f3 * m3 : f3;
            float v4 = h ? f4 * m4 : f4;
            float v5 = h ? f5 * m5 : f5;
            float v6 = h ? f6 * m6 : f6;
            float v7 = h ? f7 * m7 : f7;
            ACC_ADD(q0, v0);
            ACC_ADD(q1, v1);
            ACC_ADD(q2, v2);
            ACC_ADD(q3, v3);
            ACC_ADD(q4, v4);
            ACC_ADD(q5, v5);
            ACC_ADD(q6, v6);
            ACC_ADD(q7, v7);
        }

        // flush: one wave-wide bf16 store per k (h selects Sa/Sb region)
        __hip_bfloat16* Sp = S + (size_t)n * SPP + h * KCC + c;
#pragma unroll
        for (int k = 0; k < KC; ++k) Sp[k * CIN] = __float2bfloat16(acc[k]);
        if (lane == 0) impAcc[n] = accImp;

        start = end;                           // chained: no second rp load
    }
}
#undef ACC_ADD

// ---------------------------------------------------------------------------
// Kernel B: lane-per-point epilogue (round-10/11 winner), bf16 S input.
// W addresses wave-uniform -> s_load through K$; S per-lane row stream.
// ---------------------------------------------------------------------------
__global__ __launch_bounds__(256) void epilogue_g(
    const __hip_bfloat16* __restrict__ S, const float* __restrict__ impAcc,
    const float* __restrict__ Wc, const float* __restrict__ ba,
    const float* __restrict__ bb,
    float* __restrict__ outf, float* __restrict__ outimp, int nout)
{
    const int gtid   = blockIdx.x * 256 + threadIdx.x;
    const bool valid = (gtid < nout);
    const int n      = valid ? gtid : (nout - 1);

    const unsigned short* Sp =
        reinterpret_cast<const unsigned short*>(S + (size_t)n * SPP);

    float acc[COUT];
#pragma unroll
    for (int j = 0; j < COUT; ++j) acc[j] = 0.f;

    for (int t = 0; t < KCC; t += 8) {
        uint4 ua = *reinterpret_cast<const uint4*>(Sp + t);
        uint4 ub = *reinterpret_cast<const uint4*>(Sp + KCC + t);
        unsigned int uaw[4] = {ua.x, ua.y, ua.z, ua.w};
        unsigned int ubw[4] = {ub.x, ub.y, ub.z, ub.w};
        float sav[8], sbv[8];
#pragma unroll
        for (int p = 0; p < 4; ++p) {
            sav[2 * p]     = __uint_as_float(uaw[p] << 16);
            sav[2 * p + 1] = __uint_as_float(uaw[p] & 0xffff0000u);
            sbv[2 * p]     = __uint_as_float(ubw[p] << 16);
            sbv[2 * p + 1] = __uint_as_float(ubw[p] & 0xffff0000u);
        }
#pragma unroll
        for (int u = 0; u < 8; ++u) {
            const float* w = Wc + (t + u) * COUT;   // wave-uniform -> s_load
#pragma unroll
            for (int j = 0; j < CA; ++j) acc[j] = fmaf(sav[u], w[j], acc[j]);
#pragma unroll
            for (int j = 0; j < CB; ++j)
                acc[CA + j] = fmaf(sbv[u], w[CA + j], acc[CA + j]);
        }
    }

    float impTot = impAcc[n];
    float denom  = impTot > 0.f ? impTot : 1.f;

    if (valid) {
        float res[COUT];
#pragma unroll
        for (int j = 0; j < CA; ++j) res[j] = fmaxf(acc[j] + ba[j], 0.f);
#pragma unroll
        for (int j = 0; j < CB; ++j)
            res[CA + j] = fmaxf(acc[CA + j] / denom + bb[j], 0.f);
        float4* op = reinterpret_cast<float4*>(outf + (size_t)n * COUT);
#pragma unroll
        for (int j4 = 0; j4 < 8; ++j4)
            op[j4] = make_float4(res[4 * j4], res[4 * j4 + 1],
                                 res[4 * j4 + 2], res[4 * j4 + 3]);
        outimp[n] = impTot;
    }
}

// ===========================================================================
// Fallback (round-6 fused kernel) if ws can't hold the scratch.
// ===========================================================================
static constexpr int WSTR = KC * CIN + 4;
static constexpr int PPB = 16;
static constexpr int TPB = 512;
static constexpr int NHW = TPB / 32;

__global__ void build_rowptr_fb(const int* __restrict__ oidx, int* __restrict__ rp,
                                int E, int nout) {
    int e = blockIdx.x * blockDim.x + threadIdx.x;
    if (e >= E) return;
    int cur  = oidx[e];
    int prev = (e == 0) ? -1 : oidx[e - 1];
    for (int id = prev + 1; id <= cur; ++id) rp[id] = e;
    if (e == E - 1) {
        for (int id = cur + 1; id <= nout; ++id) rp[id] = E;
    }
}

__global__ void pack_weights_fkc(const float* __restrict__ Wa,
                                 const float* __restrict__ Wb,
                                 float* __restrict__ Wt) {
    int t = blockIdx.x * blockDim.x + threadIdx.x;
    if (t >= COUT * KC * CIN) return;
    int f = t / (KC * CIN);
    int r = t % (KC * CIN);
    Wt[t] = (f < CA) ? Wa[r * CA + f] : Wb[r * CB + (f - CA)];
}

__global__ __launch_bounds__(TPB) void fused_block(
    const float* __restrict__ feats, const float* __restrict__ importance,
    const float* __restrict__ Wt, const float* __restrict__ ba,
    const float* __restrict__ bb,
    const int* __restrict__ nidx, const int* __restrict__ nkidx,
    const int* __restrict__ noidx, const int* __restrict__ rp,
    float* __restrict__ outf, float* __restrict__ outimp, int nout)
{
    __shared__ __align__(16) float sW[COUT * WSTR];
    __shared__ __align__(16) float sS[PPB][2][KC * CIN];
    __shared__ float sImp[PPB];

    const int tid = threadIdx.x;
    const int hw  = tid >> 5;
    const int c   = tid & 31;
    const int p0  = blockIdx.x * PPB;

    {
        float* pS = &sS[0][0][0];
        for (int i = tid; i < PPB * 2 * KC * CIN; i += TPB) pS[i] = 0.f;
        for (int i = tid; i < COUT * KC * CIN; i += TPB) {
            int f = i / (KC * CIN);
            int r = i % (KC * CIN);
            sW[f * WSTR + r] = Wt[i];
        }
        if (tid < PPB) sImp[tid] = 0.f;
    }
    __syncthreads();

    const int pend   = (p0 + PPB < nout) ? (p0 + PPB) : nout;
    const int estart = rp[p0];
    const int eend   = rp[pend];
    const int cnt    = eend - estart;
    const int per    = (cnt + NHW - 1) / NHW;
    int a = estart + hw * per;
    int b = a + per; if (b > eend) b = eend;

    float* S0 = &sS[0][0][0];
    for (int e = a; e < b; ++e) {
        int   n0 = noidx[e], i0 = nidx[e], q0 = nkidx[e];
        float m0 = importance[i0];
        float f0 = feats[(size_t)i0 * CIN + c];
        float* bp = S0 + (n0 - p0) * (2 * KC * CIN) + q0 * CIN + c;
        atomicAdd(bp, f0);
        atomicAdd(bp + KC * CIN, f0 * m0);
        if (c == 0) atomicAdd(&sImp[n0 - p0], m0);
    }
    __syncthreads();

    const int wave = tid >> 6;
    const int lane = tid & 63;
    const int f    = lane & 31;
    const int h    = lane >> 5;
#pragma unroll
    for (int rep = 0; rep < 2; ++rep) {
        const int slot = wave * 2 + rep;
        const int n    = p0 + slot;
        if (n >= nout) break;
        float impTot = sImp[slot];
        float denom  = impTot > 0.f ? impTot : 1.f;
        const float* Sbase = &sS[slot][(f < CA) ? 0 : 1][0];
        const float* Wbase = sW + f * WSTR;
        float acc = 0.f;
#pragma unroll
        for (int k = 0; k < KC; ++k) {
            int off = k * CIN + h * 16;
#pragma unroll
            for (int j = 0; j < 16; ++j) acc = fmaf(Sbase[off + j], Wbase[off + j], acc);
        }
        float tot = acc + __shfl_xor(acc, 32, 64);
        if (h == 0) {
            float res = (f < CA) ? (tot + ba[f]) : (tot / denom + bb[f - CA]);
            outf[(size_t)n * COUT + f] = fmaxf(res, 0.f);
        }
        if (lane == 0) outimp[n] = impTot;
    }
}

// ---------------------------------------------------------------------------
extern "C" void kernel_launch(void* const* d_in, const int* in_sizes, int n_in,
                              void* d_out, int out_size, void* d_ws, size_t ws_size,
                              hipStream_t stream) {
    const float* feats      = (const float*)d_in[0];
    const float* importance = (const float*)d_in[1];
    const float* Wa         = (const float*)d_in[2];
    const float* ba         = (const float*)d_in[3];
    const float* Wb         = (const float*)d_in[4];
    const float* bb         = (const float*)d_in[5];
    const int*   nidx       = (const int*)d_in[6];
    const int*   nkidx      = (const int*)d_in[7];
    const int*   noidx      = (const int*)d_in[8];

    const int E    = in_sizes[6];
    const int nout = out_size / (COUT + 1);

    float* outf   = (float*)d_out;
    float* outimp = outf + (size_t)nout * COUT;

    // ws: S bf16 [nout*576] | impAcc [nout] | Wc [288*32] | rp [nout+1] | imp_e [E]
    const size_t off_imp = ((size_t)nout * SPP * sizeof(__hip_bfloat16) + 255) & ~(size_t)255;
    const size_t off_wc  = (off_imp + (size_t)nout * sizeof(float) + 255) & ~(size_t)255;
    const size_t off_rp  = (off_wc + (size_t)KCC * COUT * sizeof(float) + 255) & ~(size_t)255;
    const size_t off_ie  = (off_rp + (size_t)(nout + 1) * sizeof(int) + 255) & ~(size_t)255;
    const size_t need    = off_ie + (size_t)E * sizeof(float);

    if (ws_size >= need) {
        __hip_bfloat16* S = (__hip_bfloat16*)d_ws;
        float* impAcc = (float*)((char*)d_ws + off_imp);
        float* Wc     = (float*)((char*)d_ws + off_wc);
        int*   rp     = (int*)((char*)d_ws + off_rp);
        float* imp_e  = (float*)((char*)d_ws + off_ie);

        prep<<<(E + 255) / 256, 256, 0, stream>>>(
            noidx, nidx, importance, Wa, Wb, rp, imp_e, Wc, E, nout);
        const int nwaves  = (nout + PPW - 1) / PPW;
        const int nblocks = (nwaves + 3) / 4;
        accum_w<<<nblocks, 256, 0, stream>>>(
            feats, imp_e, nidx, nkidx, rp, S, impAcc, nout);
        epilogue_g<<<(nout + 255) / 256, 256, 0, stream>>>(
            S, impAcc, Wc, ba, bb, outf, outimp, nout);
    } else {
        int*   rp = (int*)d_ws;
        size_t rp_bytes = ((size_t)(nout + 1) * sizeof(int) + 255) & ~(size_t)255;
        float* Wt = (float*)((char*)d_ws + rp_bytes);

        build_rowptr_fb<<<(E + 255) / 256, 256, 0, stream>>>(noidx, rp, E, nout);
        pack_weights_fkc<<<(COUT * KC * CIN + 255) / 256, 256, 0, stream>>>(Wa, Wb, Wt);
        fused_block<<<(nout + PPB - 1) / PPB, TPB, 0, stream>>>(
            feats, importance, Wt, ba, bb, nidx, nkidx, noidx, rp,
            outf, outimp, nout);
    }
}